// Round 14
// baseline (125.602 us; speedup 1.0000x reference)
//
#include <hip/hip_runtime.h>
#include <cstdint>

// CIN chain: B=1024, F0=32, EMB=64, layers 128/128/128.
// cur[b,k,e] = sum_{i,j} x[b,i,e]*h[b,j,e]*W[i*fi+j,k]
//
// R26: R25 + DEEP af PREFETCH + (256,1). R25 (123.8, correct) is
// latency-bound: wave-per-batch caps at 4 waves/CU (1/SIMD), and
// Little's law needs ~17 KB in flight/CU to sustain the 1.5 MB/CU L2
// Wt stream (135 GB/s/CU share, ~300cy lat); dist-1 gave a marginal
// 16 KB and a lone wave/SIMD has no co-resident cover. Changes:
//  * kloop: 4-slot af rotation, issue distance 2 bodies -> 32 KB/CU
//    in flight (2x requirement). (R21's same shape was null at 12
//    waves/CU — wrong regime; here latency is exposed, rule #23.)
//  * cin_fused __launch_bounds__(256,1): grid-capped at 1 wave/SIMD
//    anyway; frees VGPR to 512 so the ~180-reg live set doesn't get
//    squeezed into the 128 bracket (R22 spill trap).
// Everything else identical to R25: j-major Wt' (chunk c = j, kk = i),
// B-frag = xF(regs) * broadcast(h scalar), 1 wave = 1 batch, ZERO
// barriers, S j-major with half4 stores, direct/pack unchanged.
// LDS: per wave hB 9216 (xJ->hJ1->hJ2, p72) + xT 5120 (p40); block
// 4 waves = 57344 B.

typedef _Float16 half8  __attribute__((ext_vector_type(8)));
typedef _Float16 half4_ __attribute__((ext_vector_type(4)));
typedef _Float16 half2_ __attribute__((ext_vector_type(2)));
typedef float    f32x4  __attribute__((ext_vector_type(4)));

// Pack W (fan_in,128) f32 -> j-major chunked f16:
// Wt'[c][m][kk] = W[kk*fi + c][m];  fi=32 (L0) / 64 (L1,L2).
__global__ void pack_w_all(const float* __restrict__ W0, _Float16* __restrict__ Wt0,
                           const float* __restrict__ W1, _Float16* __restrict__ Wt1,
                           const float* __restrict__ W2, _Float16* __restrict__ Wt2)
{
    __shared__ _Float16 ldsT[128 * 33];
    const int blk = blockIdx.x, t = threadIdx.x;
    const float* W;
    _Float16* Wt;
    int c, fi;
    if (blk < 32)       { W = W0; Wt = Wt0; c = blk;      fi = 32; }
    else if (blk < 96)  { W = W1; Wt = Wt1; c = blk - 32; fi = 64; }
    else                { W = W2; Wt = Wt2; c = blk - 96; fi = 64; }

    for (int p = t; p < 32 * 128; p += 256) {
        int kk = p >> 7, m = p & 127;
        ldsT[m * 33 + kk] = (_Float16)W[(size_t)(kk * fi + c) * 128 + m];
    }
    __syncthreads();
    int m = t >> 1, kk0 = (t & 1) * 16;
    half8 v0, v1;
#pragma unroll
    for (int i = 0; i < 8; ++i) {
        v0[i] = ldsT[m * 33 + kk0 + i];
        v1[i] = ldsT[m * 33 + kk0 + 8 + i];
    }
    *(half8*)(Wt + (size_t)c * 4096 + t * 16)     = v0;
    *(half8*)(Wt + (size_t)c * 4096 + t * 16 + 8) = v1;
}

// kloop: all 64 hidden rows, full K, one wave. Chunk c = j; B-frag =
// xF[nt] (registers) * broadcast(hB[c*72 + nt*16 + lr]).
// 4-slot af rotation, issue distance 2 bodies (NCH % 4 == 0).
template<int NCH>
__device__ __forceinline__ void kloop_t(f32x4 (&acc)[4][4],
    const _Float16* __restrict__ WtL, const _Float16* __restrict__ hB,
    const half8 (&xF)[4], int lr, int q)
{
#pragma unroll
    for (int mt = 0; mt < 4; ++mt)
#pragma unroll
        for (int nt = 0; nt < 4; ++nt)
            acc[mt][nt] = f32x4{0.0f, 0.0f, 0.0f, 0.0f};

    const _Float16* aG = WtL + lr * 32 + q * 8;

    half8 afA[4], afB[4], afC[4], afD[4];
    _Float16 xsA[4], xsB[4], xsC[4], xsD[4];

    auto pf = [&](half8* af, _Float16* xs, int cc) {
        const _Float16* ag = aG + (size_t)cc * 4096;
#pragma unroll
        for (int mt = 0; mt < 4; ++mt)
            af[mt] = *(const half8*)(ag + mt * 512);
#pragma unroll
        for (int nt = 0; nt < 4; ++nt)
            xs[nt] = hB[cc * 72 + nt * 16 + lr];
    };
    auto cp = [&](half8* af, _Float16* xs) {
        __builtin_amdgcn_s_setprio(1);
#pragma unroll
        for (int nt = 0; nt < 4; ++nt) {
            half2_ xv2 = {xs[nt], xs[nt]};
            half8 xv8 = __builtin_shufflevector(xv2, xv2, 0, 1, 0, 1, 0, 1, 0, 1);
            half8 bf = xF[nt] * xv8;
#pragma unroll
            for (int mt = 0; mt < 4; ++mt)
                acc[mt][nt] = __builtin_amdgcn_mfma_f32_16x16x32_f16(
                    af[mt], bf, acc[mt][nt], 0, 0, 0);
        }
        __builtin_amdgcn_s_setprio(0);
    };

    pf(afA, xsA, 0);
    pf(afB, xsB, 1);
    for (int cc = 0; cc < NCH; cc += 4) {
        pf(afC, xsC, cc + 2);
        cp(afA, xsA);                          // body cc
        pf(afD, xsD, cc + 3);
        cp(afB, xsB);                          // body cc+1
        if (cc + 4 < NCH) pf(afA, xsA, cc + 4);
        cp(afC, xsC);                          // body cc+2
        if (cc + 5 < NCH) pf(afB, xsB, cc + 5);
        cp(afD, xsD);                          // body cc+3
    }
}

// Fused kernel: 4 waves/block, 1 wave = 1 batch, NO barriers.
__global__ __launch_bounds__(256, 1)
void cin_fused(const float* __restrict__ x,          // (1024,32,64) f32
               const _Float16* __restrict__ Wt0,
               const _Float16* __restrict__ Wt1,
               const float* __restrict__ bs0,
               const float* __restrict__ bs1,
               _Float16* __restrict__ S0,             // (1024,1024) j-major
               _Float16* __restrict__ S1,             // (1024,2048) j-major
               _Float16* __restrict__ S2)             // (1024,2048) j-major
{
    __shared__ alignas(16) char smem[57344];           // 4 x 14336
    const int t = threadIdx.x, lane = t & 63, w = t >> 6;
    const int lr = lane & 15, q = lane >> 4;
    const int batch = blockIdx.x * 4 + w;

    _Float16* hB = (_Float16*)(smem + w * 14336);          // 4608 f16 p72
    _Float16* xT = (_Float16*)(smem + w * 14336 + 9216);   // 2560 f16 p40

    // per-wave prologue: this batch's x -> hB (xJ, p72) + xT (p40)
    {
        const float4* xv = (const float4*)(x + (size_t)batch * 2048);
#pragma unroll
        for (int s = 0; s < 8; ++s) {
            int p4 = lane + s * 64;
            float4 v = xv[p4];
            int idx = p4 * 4, i = idx >> 6, e0 = idx & 63;
            _Float16 h0 = (_Float16)v.x, h1 = (_Float16)v.y;
            _Float16 h2 = (_Float16)v.z, h3 = (_Float16)v.w;
            half4_ pk = {h0, h1, h2, h3};
            *(half4_*)(hB + i * 72 + e0) = pk;
            xT[(e0 + 0) * 40 + i] = h0;
            xT[(e0 + 1) * 40 + i] = h1;
            xT[(e0 + 2) * 40 + i] = h2;
            xT[(e0 + 3) * 40 + i] = h3;
        }
    }
    // (same-wave LDS RAW: compiler inserts lgkmcnt; no barrier needed)

    // persistent fragments: xT rows (whole kernel), x A-frags for sgemm
    half8 xF[4];
#pragma unroll
    for (int nt = 0; nt < 4; ++nt)
        xF[nt] = *(const half8*)(xT + (nt * 16 + lr) * 40 + q * 8);
    const half8 aF00 = *(const half8*)(hB + lr * 72 + q * 8);
    const half8 aF01 = *(const half8*)(hB + lr * 72 + q * 8 + 32);
    const half8 aF10 = *(const half8*)(hB + (16 + lr) * 72 + q * 8);
    const half8 aF11 = *(const half8*)(hB + (16 + lr) * 72 + q * 8 + 32);

    f32x4 acc[4][4];

    // epilogue: h_next = cur + bias, all 64 rows, into hB (p72)
    auto epi = [&](const float* bs) {
#pragma unroll
        for (int mt = 0; mt < 4; ++mt) {
            const int jb = mt * 16 + q * 4;
            const float b0f = bs[jb + 0], b1f = bs[jb + 1];
            const float b2f = bs[jb + 2], b3f = bs[jb + 3];
#pragma unroll
            for (int nt = 0; nt < 4; ++nt) {
                const int e = nt * 16 + lr;
                hB[(jb + 0) * 72 + e] = (_Float16)(acc[mt][nt][0] + b0f);
                hB[(jb + 1) * 72 + e] = (_Float16)(acc[mt][nt][1] + b1f);
                hB[(jb + 2) * 72 + e] = (_Float16)(acc[mt][nt][2] + b2f);
                hB[(jb + 3) * 72 + e] = (_Float16)(acc[mt][nt][3] + b3f);
            }
        }
    };

    // S'_l[b][j*32+i] = sum_e x[i,e]*h[j,e]; vector half4 stores.
    auto sgemm = [&](int fi, _Float16* Sdst) {
        const int njt = fi >> 4;
        _Float16* Sb = Sdst + (size_t)batch * (32 * fi);
        for (int jt = 0; jt < njt; ++jt) {
            half8 bv0 = *(const half8*)(hB + (jt * 16 + lr) * 72 + q * 8);
            half8 bv1 = *(const half8*)(hB + (jt * 16 + lr) * 72 + q * 8 + 32);
            f32x4 sa = {0.0f, 0.0f, 0.0f, 0.0f};
            sa = __builtin_amdgcn_mfma_f32_16x16x32_f16(aF00, bv0, sa, 0, 0, 0);
            sa = __builtin_amdgcn_mfma_f32_16x16x32_f16(aF01, bv1, sa, 0, 0, 0);
            f32x4 sb = {0.0f, 0.0f, 0.0f, 0.0f};
            sb = __builtin_amdgcn_mfma_f32_16x16x32_f16(aF10, bv0, sb, 0, 0, 0);
            sb = __builtin_amdgcn_mfma_f32_16x16x32_f16(aF11, bv1, sb, 0, 0, 0);
            half4_ v0, v1;
#pragma unroll
            for (int r = 0; r < 4; ++r) { v0[r] = (_Float16)sa[r]; v1[r] = (_Float16)sb[r]; }
            *(half4_*)(Sb + (jt * 16 + lr) * 32 + q * 4)      = v0;
            *(half4_*)(Sb + (jt * 16 + lr) * 32 + 16 + q * 4) = v1;
        }
    };

    // ---- phase 0 ----  (hB = xJ)
    sgemm(32, S0);                        // S0 = x @ x^T
    kloop_t<32>(acc, Wt0, hB, xF, lr, q); // reads hB scalars (h0 = x)
    epi(bs0);                             // hB := h1
    // ---- phase 1 ----
    sgemm(64, S1);                        // S1 = x @ h1^T
    kloop_t<64>(acc, Wt1, hB, xF, lr, q);
    epi(bs1);                             // hB := h2
    sgemm(64, S2);                        // S2 = x @ h2^T
}

// Direct-output GEMM: out[b, ob+k] = S'_l[b,:] . Wt'_l[:, dm0+k] + 64*bias.
// (S' and Wt' share the j-major permutation -> dot unchanged.)
// 1024 tasks, 1 task/block, 4-way K-split across waves; wave 0 combines.
__global__ __launch_bounds__(256, 2)
void cin_direct(const _Float16* __restrict__ S0v, const _Float16* __restrict__ S1v,
                const _Float16* __restrict__ S2v,
                const _Float16* __restrict__ Wt0, const _Float16* __restrict__ Wt1,
                const _Float16* __restrict__ Wt2,
                const float* __restrict__ bs0, const float* __restrict__ bs1,
                const float* __restrict__ bs2,
                float* __restrict__ out)
{
    __shared__ f32x4 red[3][64];
    const int t = threadIdx.x, lane = t & 63, kh = t >> 6;
    const int lr = lane & 15, q = lane >> 4;
    const int task = blockIdx.x;

    const _Float16 *S, *Wt;
    const float* bias;
    int fan, nch, dm0, ob, idx;
    if (task < 256)      { S = S0v; Wt = Wt0; bias = bs0; fan = 1024; nch = 32; dm0 = 64; ob = 0;   idx = task; }
    else if (task < 512) { S = S1v; Wt = Wt1; bias = bs1; fan = 2048; nch = 64; dm0 = 64; ob = 64;  idx = task - 256; }
    else                 { S = S2v; Wt = Wt2; bias = bs2; fan = 2048; nch = 64; dm0 = 0;  ob = 128; idx = task - 512; }
    const int bt = idx & 63, kt = idx >> 6;
    const int bbase = bt * 16;
    const int hq = nch >> 2, c0 = kh * hq;

    const _Float16* aG = Wt + (size_t)(dm0 + kt * 16 + lr) * 32 + q * 8
                            + (size_t)c0 * 4096;
    const _Float16* bG = S + (size_t)(bbase + lr) * fan + q * 8 + c0 * 32;

    f32x4 acc = {0.0f, 0.0f, 0.0f, 0.0f};
    half8 aA = *(const half8*)(aG);
    half8 bA = *(const half8*)(bG);
    for (int c = 0; c < hq; c += 2) {
        half8 aB = *(const half8*)(aG + (size_t)(c + 1) * 4096);
        half8 bB = *(const half8*)(bG + (c + 1) * 32);
        acc = __builtin_amdgcn_mfma_f32_16x16x32_f16(aA, bA, acc, 0, 0, 0);
        if (c + 2 < hq) {
            aA = *(const half8*)(aG + (size_t)(c + 2) * 4096);
            bA = *(const half8*)(bG + (c + 2) * 32);
        }
        acc = __builtin_amdgcn_mfma_f32_16x16x32_f16(aB, bB, acc, 0, 0, 0);
    }
    if (kh != 0) red[kh - 1][lane] = acc;
    __syncthreads();
    if (kh == 0) {
#pragma unroll
        for (int p = 0; p < 3; ++p) {
            f32x4 o = red[p][lane];
#pragma unroll
            for (int r = 0; r < 4; ++r) acc[r] += o[r];
        }
#pragma unroll
        for (int r = 0; r < 4; ++r) {
            int kl = kt * 16 + q * 4 + r;
            out[(size_t)(bbase + lr) * 256 + ob + kl]
                = acc[r] + 64.0f * bias[dm0 + kl];
        }
    }
}

extern "C" void kernel_launch(void* const* d_in, const int* in_sizes, int n_in,
                              void* d_out, int out_size, void* d_ws, size_t ws_size,
                              hipStream_t stream)
{
    const float* x  = (const float*)d_in[0];
    const float* W0 = (const float*)d_in[1];
    const float* b0 = (const float*)d_in[2];
    const float* W1 = (const float*)d_in[3];
    const float* b1 = (const float*)d_in[4];
    const float* W2 = (const float*)d_in[5];
    const float* b2 = (const float*)d_in[6];
    float* out = (float*)d_out;

    char* ws = (char*)d_ws;
    _Float16* Wt0 = (_Float16*)(ws + 0);           // 256 KB
    _Float16* Wt1 = (_Float16*)(ws + 262144);      // 512 KB
    _Float16* Wt2 = (_Float16*)(ws + 786432);      // 512 KB
    _Float16* S0  = (_Float16*)(ws + 1310720);     // 2 MB  (1024 x 1024 f16)
    _Float16* S1  = (_Float16*)(ws + 3407872);     // 4 MB  (1024 x 2048 f16)
    _Float16* S2  = (_Float16*)(ws + 7602176);     // 4 MB
    (void)in_sizes; (void)n_in; (void)out_size; (void)ws_size;

    hipLaunchKernelGGL(pack_w_all, dim3(160), dim3(256), 0, stream,
                       W0, Wt0, W1, Wt1, W2, Wt2);

    hipLaunchKernelGGL(cin_fused, dim3(256), dim3(256), 0, stream,
                       x, Wt0, Wt1, b0, b1, S0, S1, S2);

    hipLaunchKernelGGL(cin_direct, dim3(1024), dim3(256), 0, stream,
                       S0, S1, S2, Wt0, Wt1, Wt2, b0, b1, b2, out);
}

// Round 15
// 117.461 us; speedup vs baseline: 1.0693x; 1.0693x over previous
//
#include <hip/hip_runtime.h>
#include <cstdint>

// CIN chain: B=1024, F0=32, EMB=64, layers 128/128/128.
// cur[b,k,e] = sum_{i,j} x[b,i,e]*h[b,j,e]*W[i*fi+j,k]
//
// R27: HYBRID = R23b multi-wave K-split-4 skeleton x R25 j-major kloop.
// R26 post-mortem: wave-per-batch is latency-doomed (1 wave/SIMD,
// MfmaUtil 21%, deep prefetch null) but proved the j-major algebra.
// With Wt'[c=j][m][kk=i], kloop B-frag = xF(regs, once/block) *
// broadcast(h[c][e] scalar): wave w takes j-quarter c0=w*NCH/4.
// Deleted vs R23b: 4x ds_read_b128 hv per chunk, sX buffer, hT image
// (prologue build + epi double-write). Kept vs R26: 4 waves/block,
// grid 1024 -> 12-16 waves/CU latency cover; 2-pass f32 exchange;
// 256-thr clean writes. S j-major S'[b][j*32+i]: half4 vector stores,
// and direct's dot is unchanged (Wt' rows same permutation — R25
// verified). LDS 26624 B: xT 5120 | hB 9216 | XC 12288.
//   hB: xJ(p72) -> [b1] -> hJ1 -> [b1'] -> hJ2   (rows j, cols e)
//   xT: [e][i] p40, whole kernel (xF source)
// Bounds (256,2) everywhere ((256,4) = 64-VGPR spill trap,
// R16/R18/R22).

typedef _Float16 half8  __attribute__((ext_vector_type(8)));
typedef _Float16 half4_ __attribute__((ext_vector_type(4)));
typedef _Float16 half2_ __attribute__((ext_vector_type(2)));
typedef float    f32x4  __attribute__((ext_vector_type(4)));

// Pack W (fan_in,128) f32 -> j-major chunked f16:
// Wt'[c][m][kk] = W[kk*fi + c][m];  fi=32 (L0) / 64 (L1,L2).
__global__ void pack_w_all(const float* __restrict__ W0, _Float16* __restrict__ Wt0,
                           const float* __restrict__ W1, _Float16* __restrict__ Wt1,
                           const float* __restrict__ W2, _Float16* __restrict__ Wt2)
{
    __shared__ _Float16 ldsT[128 * 33];
    const int blk = blockIdx.x, t = threadIdx.x;
    const float* W;
    _Float16* Wt;
    int c, fi;
    if (blk < 32)       { W = W0; Wt = Wt0; c = blk;      fi = 32; }
    else if (blk < 96)  { W = W1; Wt = Wt1; c = blk - 32; fi = 64; }
    else                { W = W2; Wt = Wt2; c = blk - 96; fi = 64; }

    for (int p = t; p < 32 * 128; p += 256) {
        int kk = p >> 7, m = p & 127;
        ldsT[m * 33 + kk] = (_Float16)W[(size_t)(kk * fi + c) * 128 + m];
    }
    __syncthreads();
    int m = t >> 1, kk0 = (t & 1) * 16;
    half8 v0, v1;
#pragma unroll
    for (int i = 0; i < 8; ++i) {
        v0[i] = ldsT[m * 33 + kk0 + i];
        v1[i] = ldsT[m * 33 + kk0 + 8 + i];
    }
    *(half8*)(Wt + (size_t)c * 4096 + t * 16)     = v0;
    *(half8*)(Wt + (size_t)c * 4096 + t * 16 + 8) = v1;
}

// kloop: all 64 hidden rows (mt=4), this wave's j-QUARTER.
// af from Wt' (global, 2-slot dist-1); B-frag = xF[nt] * broadcast of
// h scalar hB[c*72 + nt*16 + lr]. setprio around MFMA cluster.
template<int NCH>
__device__ __forceinline__ void kloop_t(f32x4 (&acc)[4][4],
    const _Float16* __restrict__ WtL, const _Float16* __restrict__ hB,
    const half8 (&xF)[4], int lr, int q, int w)
{
#pragma unroll
    for (int mt = 0; mt < 4; ++mt)
#pragma unroll
        for (int nt = 0; nt < 4; ++nt)
            acc[mt][nt] = f32x4{0.0f, 0.0f, 0.0f, 0.0f};

    constexpr int HC = NCH / 4;               // chunks (j's) per wave
    const int c0 = w * HC;
    const _Float16* aG = WtL + (size_t)c0 * 4096 + lr * 32 + q * 8;
    const _Float16* hP = hB + (size_t)c0 * 72 + lr;

    half8 afA[4], afB[4];
    _Float16 xsA[4], xsB[4];

    auto pf = [&](half8* af, _Float16* xs, int cc) {
        const _Float16* ag = aG + (size_t)cc * 4096;
#pragma unroll
        for (int mt = 0; mt < 4; ++mt)
            af[mt] = *(const half8*)(ag + mt * 512);
        const _Float16* hh = hP + cc * 72;
#pragma unroll
        for (int nt = 0; nt < 4; ++nt)
            xs[nt] = hh[nt * 16];
    };
    auto cp = [&](half8* af, _Float16* xs) {
        __builtin_amdgcn_s_setprio(1);
#pragma unroll
        for (int nt = 0; nt < 4; ++nt) {
            half2_ xv2 = {xs[nt], xs[nt]};
            half8 xv8 = __builtin_shufflevector(xv2, xv2, 0, 1, 0, 1, 0, 1, 0, 1);
            half8 bf = xF[nt] * xv8;
#pragma unroll
            for (int mt = 0; mt < 4; ++mt)
                acc[mt][nt] = __builtin_amdgcn_mfma_f32_16x16x32_f16(
                    af[mt], bf, acc[mt][nt], 0, 0, 0);
        }
        __builtin_amdgcn_s_setprio(0);
    };

    pf(afA, xsA, 0);
    for (int cc = 0; cc < HC; cc += 2) {
        pf(afB, xsB, cc + 1);
        cp(afA, xsA);
        if (cc + 2 < HC) pf(afA, xsA, cc + 2);
        cp(afB, xsB);
    }
}

// Fused kernel. Block = 1 batch, 256 thr = 4 waves (j-quarter w).
__global__ __launch_bounds__(256, 2)
void cin_fused(const float* __restrict__ x,          // (1024,32,64) f32
               const _Float16* __restrict__ Wt0,
               const _Float16* __restrict__ Wt1,
               const float* __restrict__ bs0,
               const float* __restrict__ bs1,
               _Float16* __restrict__ S0,             // (1024,1024) j-major
               _Float16* __restrict__ S1,             // (1024,2048) j-major
               _Float16* __restrict__ S2)             // (1024,2048) j-major
{
    __shared__ alignas(16) char smem[26624];
    _Float16* xT   = (_Float16*)smem;                  // 5120 B  [e][i] p40
    _Float16* hB   = (_Float16*)(smem + 5120);         // 9216 B  [j][e] p72
    _Float16* XC16 = (_Float16*)(smem + 14336);        // 12288 B exchange

    const int t = threadIdx.x, lane = t & 63, w = t >> 6;
    const int lr = lane & 15, q = lane >> 4;
    const int b = blockIdx.x;

    // prologue: x -> hB (xJ, p72) + xT ([e][i], p40)
    {
        const float4* xv = (const float4*)(x + (size_t)b * 2048);
#pragma unroll
        for (int s = 0; s < 2; ++s) {
            int p4 = t + s * 256;
            float4 v = xv[p4];
            int idx = p4 * 4, i = idx >> 6, e0 = idx & 63;
            _Float16 h0 = (_Float16)v.x, h1 = (_Float16)v.y;
            _Float16 h2 = (_Float16)v.z, h3 = (_Float16)v.w;
            half4_ pk = {h0, h1, h2, h3};
            *(half4_*)(hB + i * 72 + e0) = pk;
            xT[(e0 + 0) * 40 + i] = h0;
            xT[(e0 + 1) * 40 + i] = h1;
            xT[(e0 + 2) * 40 + i] = h2;
            xT[(e0 + 3) * 40 + i] = h3;
        }
    }
    __syncthreads();                                   // B0

    // persistent fragments: xF (kloop B-source, whole kernel);
    // aF pair (sgemm A, it = w&1 folds into the load ADDRESS)
    half8 xF[4];
#pragma unroll
    for (int nt = 0; nt < 4; ++nt)
        xF[nt] = *(const half8*)(xT + (nt * 16 + lr) * 40 + q * 8);
    const int it = w & 1;
    const half8 aF0 = *(const half8*)(hB + (it * 16 + lr) * 72 + q * 8);
    const half8 aF1 = *(const half8*)(hB + (it * 16 + lr) * 72 + q * 8 + 32);

    f32x4 acc[4][4];

    // exchange helpers: slot(tgt,src) = (tgt*3+src)*1024 f16 (2 KB each)
    auto xw_pair = [&](const f32x4 (&a)[4], int slot) {
#pragma unroll
        for (int cc = 0; cc < 2; ++cc) {
            half8 hv8;
#pragma unroll
            for (int r = 0; r < 4; ++r) {
                hv8[r]     = (_Float16)a[cc * 2][r];
                hv8[4 + r] = (_Float16)a[cc * 2 + 1][r];
            }
            *(half8*)(XC16 + slot * 1024 + cc * 512 + lane * 8) = hv8;
        }
    };
    auto xr_sum = [&](f32x4 (&a)[4], int tgt) {
#pragma unroll
        for (int p = 0; p < 3; ++p) {
#pragma unroll
            for (int cc = 0; cc < 2; ++cc) {
                half8 hv8 = *(const half8*)(XC16 + (tgt * 3 + p) * 1024
                                            + cc * 512 + lane * 8);
#pragma unroll
                for (int r = 0; r < 4; ++r) {
                    a[cc * 2][r]     += (float)hv8[r];
                    a[cc * 2 + 1][r] += (float)hv8[4 + r];
                }
            }
        }
    };

    // epilogue for this wave's 16 rows (w*16 + q*4 ..): hJ only
    auto epi_rows = [&](const f32x4 (&a)[4], const float* bs) {
        const int jb = w * 16 + q * 4;
        const float b0f = bs[jb + 0], b1f = bs[jb + 1];
        const float b2f = bs[jb + 2], b3f = bs[jb + 3];
#pragma unroll
        for (int nt = 0; nt < 4; ++nt) {
            const int e = nt * 16 + lr;
            hB[(jb + 0) * 72 + e] = (_Float16)(a[nt][0] + b0f);
            hB[(jb + 1) * 72 + e] = (_Float16)(a[nt][1] + b1f);
            hB[(jb + 2) * 72 + e] = (_Float16)(a[nt][2] + b2f);
            hB[(jb + 3) * 72 + e] = (_Float16)(a[nt][3] + b3f);
        }
    };

    // 2-pass combine+epilogue (pass1 rows 0..31, waves 0/1; pass2
    // rows 32..63, waves 2/3). Wave-uniform branches only.
    auto combine_epi = [&](const float* bs) {
        if (w == 0)      { xw_pair(acc[1], 3); }
        else if (w == 1) { xw_pair(acc[0], 0); }
        else if (w == 2) { xw_pair(acc[0], 1); xw_pair(acc[1], 4); }
        else             { xw_pair(acc[0], 2); xw_pair(acc[1], 5); }
        __syncthreads();                             // b1
        if (w == 0)      { xr_sum(acc[0], 0); epi_rows(acc[0], bs); }
        else if (w == 1) { xr_sum(acc[1], 1); epi_rows(acc[1], bs); }
        __syncthreads();                             // b2
        if (w == 0)      { xw_pair(acc[2], 0); xw_pair(acc[3], 3); }
        else if (w == 1) { xw_pair(acc[2], 1); xw_pair(acc[3], 4); }
        else if (w == 2) { xw_pair(acc[3], 5); }
        else             { xw_pair(acc[2], 2); }
        __syncthreads();                             // b3
        if (w == 2)      { xr_sum(acc[2], 0); epi_rows(acc[2], bs); }
        else if (w == 3) { xr_sum(acc[3], 1); epi_rows(acc[3], bs); }
    };

    // S'_l[b][j*32+i] = sum_e x[i,e]*h[j,e]; tiles split across waves,
    // i-tile = it (aF), jt varies; j-major half4 vector stores.
    auto sgemm = [&](int fi, _Float16* Sdst) {
        const int nT = fi >> 3;                        // 4 or 8 tiles
        _Float16* Sb = Sdst + (size_t)b * (32 * fi);
        for (int tt = w; tt < nT; tt += 4) {
            const int jt = tt >> 1;
            f32x4 sa = {0.0f, 0.0f, 0.0f, 0.0f};
            half8 bv0 = *(const half8*)(hB + (jt * 16 + lr) * 72 + q * 8);
            half8 bv1 = *(const half8*)(hB + (jt * 16 + lr) * 72 + q * 8 + 32);
            sa = __builtin_amdgcn_mfma_f32_16x16x32_f16(aF0, bv0, sa, 0, 0, 0);
            sa = __builtin_amdgcn_mfma_f32_16x16x32_f16(aF1, bv1, sa, 0, 0, 0);
            half4_ v0;
#pragma unroll
            for (int r = 0; r < 4; ++r) v0[r] = (_Float16)sa[r];
            *(half4_*)(Sb + (jt * 16 + lr) * 32 + it * 16 + q * 4) = v0;
        }
    };

    // ---- phase 0 ----  (hB = xJ; kloop chunk c = j of x)
    sgemm(32, S0);                            // S0' = j-major x @ x^T
    kloop_t<32>(acc, Wt0, hB, xF, lr, q, w);
    combine_epi(bs0);                         // hB := h1
    __syncthreads();                          // B2
    // ---- phase 1 ----
    sgemm(64, S1);                            // S1' = j-major x @ h1^T
    kloop_t<64>(acc, Wt1, hB, xF, lr, q, w);
    combine_epi(bs1);                         // hB := h2
    __syncthreads();                          // B4
    sgemm(64, S2);                            // S2' = j-major x @ h2^T
}

// Direct-output GEMM: out[b, ob+k] = S'_l[b,:] . Wt'_l[:, dm0+k] + 64*bias.
// (S' and Wt' share the j-major permutation -> dot unchanged.)
// 1024 tasks, 1 task/block, 4-way K-split across waves; wave 0 combines.
__global__ __launch_bounds__(256, 2)
void cin_direct(const _Float16* __restrict__ S0v, const _Float16* __restrict__ S1v,
                const _Float16* __restrict__ S2v,
                const _Float16* __restrict__ Wt0, const _Float16* __restrict__ Wt1,
                const _Float16* __restrict__ Wt2,
                const float* __restrict__ bs0, const float* __restrict__ bs1,
                const float* __restrict__ bs2,
                float* __restrict__ out)
{
    __shared__ f32x4 red[3][64];
    const int t = threadIdx.x, lane = t & 63, kh = t >> 6;
    const int lr = lane & 15, q = lane >> 4;
    const int task = blockIdx.x;

    const _Float16 *S, *Wt;
    const float* bias;
    int fan, nch, dm0, ob, idx;
    if (task < 256)      { S = S0v; Wt = Wt0; bias = bs0; fan = 1024; nch = 32; dm0 = 64; ob = 0;   idx = task; }
    else if (task < 512) { S = S1v; Wt = Wt1; bias = bs1; fan = 2048; nch = 64; dm0 = 64; ob = 64;  idx = task - 256; }
    else                 { S = S2v; Wt = Wt2; bias = bs2; fan = 2048; nch = 64; dm0 = 0;  ob = 128; idx = task - 512; }
    const int bt = idx & 63, kt = idx >> 6;
    const int bbase = bt * 16;
    const int hq = nch >> 2, c0 = kh * hq;

    const _Float16* aG = Wt + (size_t)(dm0 + kt * 16 + lr) * 32 + q * 8
                            + (size_t)c0 * 4096;
    const _Float16* bG = S + (size_t)(bbase + lr) * fan + q * 8 + c0 * 32;

    f32x4 acc = {0.0f, 0.0f, 0.0f, 0.0f};
    half8 aA = *(const half8*)(aG);
    half8 bA = *(const half8*)(bG);
    for (int c = 0; c < hq; c += 2) {
        half8 aB = *(const half8*)(aG + (size_t)(c + 1) * 4096);
        half8 bB = *(const half8*)(bG + (c + 1) * 32);
        acc = __builtin_amdgcn_mfma_f32_16x16x32_f16(aA, bA, acc, 0, 0, 0);
        if (c + 2 < hq) {
            aA = *(const half8*)(aG + (size_t)(c + 2) * 4096);
            bA = *(const half8*)(bG + (c + 2) * 32);
        }
        acc = __builtin_amdgcn_mfma_f32_16x16x32_f16(aB, bB, acc, 0, 0, 0);
    }
    if (kh != 0) red[kh - 1][lane] = acc;
    __syncthreads();
    if (kh == 0) {
#pragma unroll
        for (int p = 0; p < 3; ++p) {
            f32x4 o = red[p][lane];
#pragma unroll
            for (int r = 0; r < 4; ++r) acc[r] += o[r];
        }
#pragma unroll
        for (int r = 0; r < 4; ++r) {
            int kl = kt * 16 + q * 4 + r;
            out[(size_t)(bbase + lr) * 256 + ob + kl]
                = acc[r] + 64.0f * bias[dm0 + kl];
        }
    }
}

extern "C" void kernel_launch(void* const* d_in, const int* in_sizes, int n_in,
                              void* d_out, int out_size, void* d_ws, size_t ws_size,
                              hipStream_t stream)
{
    const float* x  = (const float*)d_in[0];
    const float* W0 = (const float*)d_in[1];
    const float* b0 = (const float*)d_in[2];
    const float* W1 = (const float*)d_in[3];
    const float* b1 = (const float*)d_in[4];
    const float* W2 = (const float*)d_in[5];
    const float* b2 = (const float*)d_in[6];
    float* out = (float*)d_out;

    char* ws = (char*)d_ws;
    _Float16* Wt0 = (_Float16*)(ws + 0);           // 256 KB
    _Float16* Wt1 = (_Float16*)(ws + 262144);      // 512 KB
    _Float16* Wt2 = (_Float16*)(ws + 786432);      // 512 KB
    _Float16* S0  = (_Float16*)(ws + 1310720);     // 2 MB  (1024 x 1024 f16)
    _Float16* S1  = (_Float16*)(ws + 3407872);     // 4 MB  (1024 x 2048 f16)
    _Float16* S2  = (_Float16*)(ws + 7602176);     // 4 MB
    (void)in_sizes; (void)n_in; (void)out_size; (void)ws_size;

    hipLaunchKernelGGL(pack_w_all, dim3(160), dim3(256), 0, stream,
                       W0, Wt0, W1, Wt1, W2, Wt2);

    hipLaunchKernelGGL(cin_fused, dim3(1024), dim3(256), 0, stream,
                       x, Wt0, Wt1, b0, b1, S0, S1, S2);

    hipLaunchKernelGGL(cin_direct, dim3(1024), dim3(256), 0, stream,
                       S0, S1, S2, Wt0, Wt1, Wt2, b0, b1, b2, out);
}